// Round 1
// baseline (845.022 us; speedup 1.0000x reference)
//
#include <hip/hip_runtime.h>

#define NODES 100000
#define SCAN_B 200
#define CHUNK 500

typedef __attribute__((ext_vector_type(4))) float f4v;
typedef __attribute__((ext_vector_type(8))) short bfx8;
typedef __attribute__((ext_vector_type(4))) float f32x4;
typedef __attribute__((ext_vector_type(4))) unsigned short us4v;
typedef __attribute__((ext_vector_type(2))) unsigned int u2v;
typedef unsigned short ushort_t;
typedef unsigned int uint_t;

__device__ __forceinline__ ushort_t f2b(float f) {
  union { float f; uint_t u; } v; v.f = f;
  return (ushort_t)((v.u + 0x7fffu + ((v.u >> 16) & 1u)) >> 16);
}

#define MFMA16(A, B, C) __builtin_amdgcn_mfma_f32_16x16x32_bf16((A), (B), (C), 0, 0, 0)

// ---------------- graph prep ----------------

__global__ void count_deg(const int* __restrict__ dst, int* __restrict__ deg, int E) {
  int i = blockIdx.x * 256 + threadIdx.x;
  if (i < E) atomicAdd(&deg[dst[i]], 1);
}

__global__ void dinv_k(const int* __restrict__ deg, float* __restrict__ dinv, int n) {
  int i = blockIdx.x * 256 + threadIdx.x;
  if (i < n) dinv[i] = 1.0f / sqrtf((float)(deg[i] + 1));
}

__global__ void scan_sum(const int* __restrict__ deg, int* __restrict__ bsum) {
  __shared__ int sh[256];
  int b = blockIdx.x, t = threadIdx.x;
  int base = b * CHUNK;
  int v = 0;
  for (int i = t; i < CHUNK; i += 256) v += deg[base + i];
  sh[t] = v;
  __syncthreads();
  for (int s = 128; s > 0; s >>= 1) {
    if (t < s) sh[t] += sh[t + s];
    __syncthreads();
  }
  if (t == 0) bsum[b] = sh[0];
}

__global__ void scan_top(int* __restrict__ bsum) {
  __shared__ int sh[SCAN_B];
  int t = threadIdx.x;
  if (t < SCAN_B) sh[t] = bsum[t];
  __syncthreads();
  if (t == 0) {
    int run = 0;
    for (int i = 0; i < SCAN_B; ++i) { int x = sh[i]; sh[i] = run; run += x; }
  }
  __syncthreads();
  if (t < SCAN_B) bsum[t] = sh[t];
}

__global__ void scan_out(const int* __restrict__ deg, const int* __restrict__ bsum,
                         int* __restrict__ row_start, int E) {
  __shared__ int sh[CHUNK];
  int b = blockIdx.x, t = threadIdx.x;
  int base = b * CHUNK;
  for (int i = t; i < CHUNK; i += 256) sh[i] = deg[base + i];
  __syncthreads();
  if (t == 0) {
    int run = bsum[b];
    for (int i = 0; i < CHUNK; ++i) { int x = sh[i]; sh[i] = run; run += x; }
  }
  __syncthreads();
  for (int i = t; i < CHUNK; i += 256) row_start[base + i] = sh[i];
  if (b == SCAN_B - 1 && t == 0) row_start[NODES] = E;
}

__global__ void fill_csr(const int* __restrict__ src, const int* __restrict__ dst,
                         const int* __restrict__ row_start, int* __restrict__ cursor,
                         int* __restrict__ csr, int E) {
  int i = blockIdx.x * 256 + threadIdx.x;
  if (i < E) {
    int d = dst[i];
    int p = atomicAdd(&cursor[d], 1);
    csr[row_start[d] + p] = src[i];
  }
}

// ---------------- conv path (fp32) ----------------

// out[r][c] = dinv[r] * sum_k A[r][k]*W[k][c], 64 output cols
__global__ __launch_bounds__(256) void gemm_scaled(
    const float* __restrict__ A, const float* __restrict__ W,
    const float* __restrict__ dinv, float* __restrict__ out, int n, int K) {
  int tid = threadIdx.x;
  int cg = tid & 15, rg = tid >> 4;
  int row0 = blockIdx.x * 64 + rg * 4;
  f4v acc[4];
#pragma unroll
  for (int r = 0; r < 4; ++r) acc[r] = (f4v){0.f, 0.f, 0.f, 0.f};
  bool full = (blockIdx.x * 64 + 64 <= n);
  for (int k0 = 0; k0 < K; k0 += 4) {
    f4v wv0 = *(const f4v*)(W + (size_t)(k0 + 0) * 64 + cg * 4);
    f4v wv1 = *(const f4v*)(W + (size_t)(k0 + 1) * 64 + cg * 4);
    f4v wv2 = *(const f4v*)(W + (size_t)(k0 + 2) * 64 + cg * 4);
    f4v wv3 = *(const f4v*)(W + (size_t)(k0 + 3) * 64 + cg * 4);
#pragma unroll
    for (int r = 0; r < 4; ++r) {
      int row = row0 + r;
      if (full || row < n) {
        f4v xv = *(const f4v*)(A + (size_t)row * K + k0);
        acc[r] += xv[0] * wv0 + xv[1] * wv1 + xv[2] * wv2 + xv[3] * wv3;
      }
    }
  }
#pragma unroll
  for (int r = 0; r < 4; ++r) {
    int row = row0 + r;
    if (row < n) {
      float s = dinv[row];
      f4v o = acc[r] * s;
      *(f4v*)(out + (size_t)row * 64 + cg * 4) = o;
    }
  }
}

// out[i][c] = relu( dinv[i] * (P[i][c] + sum_{s in nbr(i)} P[s][c]) + bias[c] )
__global__ void agg_k(const float* __restrict__ P, const int* __restrict__ row_start,
                      const int* __restrict__ csr, const float* __restrict__ dinv,
                      const float* __restrict__ bias, float* __restrict__ out, int n) {
  int wave = threadIdx.x >> 6, lane = threadIdx.x & 63;
  int i = blockIdx.x * 4 + wave;
  if (i >= n) return;
  float acc = P[(size_t)i * 64 + lane];
  int beg = row_start[i], end = row_start[i + 1];
  float di = dinv[i];
  for (int j = beg; j < end; ++j) {
    int s = csr[j];
    acc += P[(size_t)s * 64 + lane];
  }
  out[(size_t)i * 64 + lane] = fmaxf(acc * di + bias[lane], 0.0f);
}

__global__ void cvt_k(const float* __restrict__ in, ushort_t* __restrict__ o, int n) {
  int i = (blockIdx.x * 256 + threadIdx.x) * 4;
  if (i >= n) return;
  f4v v = *(const f4v*)(in + i);
  us4v r;
#pragma unroll
  for (int j = 0; j < 4; ++j) r[j] = f2b(v[j]);
  *(us4v*)(o + i) = r;
}

// ---------------- edge MLP (bf16 MFMA) ----------------
// per wave-iter: 32 edges. GEMM1: h1T = Wp1^T(A) x feat^T(B); GEMM2: Wp2 frags in regs.
__global__ __launch_bounds__(256, 2) void mlp_kernel(
    const int* __restrict__ ei, const ushort_t* __restrict__ zb,
    const float* __restrict__ Wp1, const float* __restrict__ bp1,
    const float* __restrict__ Wp2, const float* __restrict__ bp2,
    const float* __restrict__ Wp3, const float* __restrict__ bp3,
    float* __restrict__ out, int E) {
  __shared__ __align__(16) char WT1[32768];      // Wp1^T, [n=128][k=128] bf16, XOR-swizzled rows
  __shared__ __align__(16) char H1[4][8192];     // per-wave h1, [edge=32][n=128] bf16, swizzled

  int tid = threadIdx.x;
  // stage Wp1^T (swizzle: byte ^= (row&7)<<4 within 256B row)
  for (int idx = tid; idx < 128 * 128; idx += 256) {
    int k = idx >> 7, n = idx & 127;
    int boff = n * 256 + (((k * 2) ^ ((n & 7) << 4)));
    *(ushort_t*)(WT1 + boff) = f2b(Wp1[idx]);
  }
  __syncthreads();

  int lane = tid & 63, wave = tid >> 6;
  int q = lane & 15, g = lane >> 4;
  char* H1w = &H1[wave][0];

  // GEMM2 weight frags in registers (A-frag: row n2=t2*16+q, k=kk*32+g*8+j)
  bfx8 wf2r[16];
#pragma unroll
  for (int t2 = 0; t2 < 4; ++t2)
#pragma unroll
    for (int kk = 0; kk < 4; ++kk) {
      bfx8 v;
#pragma unroll
      for (int j = 0; j < 8; ++j) {
        int k = kk * 32 + g * 8 + j;
        int n = t2 * 16 + q;
        v[j] = (short)f2b(Wp2[k * 64 + n]);
      }
      wf2r[t2 * 4 + kk] = v;
    }
  float b1r[32], b2r[16], w3r[16];
#pragma unroll
  for (int t = 0; t < 8; ++t)
#pragma unroll
    for (int j = 0; j < 4; ++j) b1r[t * 4 + j] = bp1[t * 16 + g * 4 + j];
#pragma unroll
  for (int t = 0; t < 4; ++t)
#pragma unroll
    for (int j = 0; j < 4; ++j) {
      b2r[t * 4 + j] = bp2[t * 16 + g * 4 + j];
      w3r[t * 4 + j] = Wp3[t * 16 + g * 4 + j];
    }
  float bp3v = bp3[0];

  int ntile = E >> 7;  // 128 edges per block-iter (4 waves x 32)
  for (int tile = blockIdx.x; tile < ntile; tile += gridDim.x) {
    int ebase = (tile << 7) + (wave << 5);

    // feat B-frags straight from global z_bf16: col=edge(q), k=kk*32+g*8+j
    bfx8 af[2][4];
#pragma unroll
    for (int eb = 0; eb < 2; ++eb) {
      int e = ebase + eb * 16 + q;
      int s = ei[e], d = ei[E + e];
#pragma unroll
      for (int kk = 0; kk < 4; ++kk) {
        int node = (kk < 2) ? s : d;
        int off = ((kk & 1) << 5) + (g << 3);
        af[eb][kk] = *(const bfx8*)(zb + (size_t)node * 64 + off);
      }
    }

    // GEMM1: t-outer so acc1 stays tiny; write h1 tile t to LDS as we go
#pragma unroll
    for (int t = 0; t < 8; ++t) {
      f32x4 acc1[2];
      acc1[0] = (f32x4){0.f, 0.f, 0.f, 0.f};
      acc1[1] = (f32x4){0.f, 0.f, 0.f, 0.f};
#pragma unroll
      for (int kk = 0; kk < 4; ++kk) {
        int n = t * 16 + q;
        bfx8 wf = *(const bfx8*)(WT1 + n * 256 + (((kk * 64 + g * 16)) ^ ((n & 7) << 4)));
        acc1[0] = MFMA16(wf, af[0][kk], acc1[0]);
        acc1[1] = MFMA16(wf, af[1][kk], acc1[1]);
      }
      // lane holds h1[edge = eb*16+q][n = t*16 + g*4 + j], j=0..3
#pragma unroll
      for (int eb = 0; eb < 2; ++eb) {
        float v0 = fmaxf(acc1[eb][0] + b1r[t * 4 + 0], 0.f);
        float v1 = fmaxf(acc1[eb][1] + b1r[t * 4 + 1], 0.f);
        float v2 = fmaxf(acc1[eb][2] + b1r[t * 4 + 2], 0.f);
        float v3 = fmaxf(acc1[eb][3] + b1r[t * 4 + 3], 0.f);
        u2v pk;
        pk[0] = (uint_t)f2b(v0) | ((uint_t)f2b(v1) << 16);
        pk[1] = (uint_t)f2b(v2) | ((uint_t)f2b(v3) << 16);
        int row = eb * 16 + q;
        int bcol = ((t * 32 + g * 8)) ^ ((row & 7) << 4);
        *(u2v*)(H1w + row * 256 + bcol) = pk;
      }
    }
    asm volatile("s_waitcnt lgkmcnt(0)" ::: "memory");

    // GEMM2 + final dot
#pragma unroll
    for (int eb = 0; eb < 2; ++eb) {
      f32x4 acc2[4];
#pragma unroll
      for (int t2 = 0; t2 < 4; ++t2) acc2[t2] = (f32x4){0.f, 0.f, 0.f, 0.f};
#pragma unroll
      for (int kk = 0; kk < 4; ++kk) {
        int row = eb * 16 + q;
        bfx8 hf = *(const bfx8*)(H1w + row * 256 + (((kk * 64 + g * 16)) ^ ((row & 7) << 4)));
#pragma unroll
        for (int t2 = 0; t2 < 4; ++t2) acc2[t2] = MFMA16(wf2r[t2 * 4 + kk], hf, acc2[t2]);
      }
      float sacc = 0.f;
#pragma unroll
      for (int t2 = 0; t2 < 4; ++t2)
#pragma unroll
        for (int j = 0; j < 4; ++j) {
          float h = fmaxf(acc2[t2][j] + b2r[t2 * 4 + j], 0.f);
          sacc += h * w3r[t2 * 4 + j];
        }
      sacc += __shfl_xor(sacc, 16);
      sacc += __shfl_xor(sacc, 32);
      if (g == 0) out[ebase + eb * 16 + q] = sacc + bp3v;
    }
  }
}

// ---------------- launch ----------------

static inline size_t alup(size_t x) { return (x + 511) & ~(size_t)511; }

extern "C" void kernel_launch(void* const* d_in, const int* in_sizes, int n_in,
                              void* d_out, int out_size, void* d_ws, size_t ws_size,
                              hipStream_t stream) {
  const float* x = (const float*)d_in[0];
  const int* ei = (const int*)d_in[1];
  const int* nei = (const int*)d_in[2];
  const float* W1 = (const float*)d_in[3];
  const float* b1 = (const float*)d_in[4];
  const float* W2 = (const float*)d_in[5];
  const float* b2 = (const float*)d_in[6];
  const float* Wp1 = (const float*)d_in[7];
  const float* bp1 = (const float*)d_in[8];
  const float* Wp2 = (const float*)d_in[9];
  const float* bp2 = (const float*)d_in[10];
  const float* Wp3 = (const float*)d_in[11];
  const float* bp3 = (const float*)d_in[12];

  const int N = NODES;
  const int E = in_sizes[1] / 2;

  float* pos = (float*)d_out;
  float* neg = pos + E;
  float* z = pos + (size_t)2 * E;

  char* w = (char*)d_ws;
  size_t off = 0;
  int* deg = (int*)(w + off); off = alup(off + (size_t)N * 4);
  int* cur = (int*)(w + off); off = alup(off + (size_t)N * 4);
  float* dinv = (float*)(w + off); off = alup(off + (size_t)N * 4);
  int* bsum = (int*)(w + off); off = alup(off + 256 * 4);
  int* row_start = (int*)(w + off); off = alup(off + (size_t)(N + 1) * 4);
  int* csr = (int*)(w + off); off = alup(off + (size_t)E * 4);
  float* xw = (float*)(w + off); off = alup(off + (size_t)N * 64 * 4);
  float* z1 = (float*)(w + off); off = alup(off + (size_t)N * 64 * 4);
  ushort_t* zb = (ushort_t*)(w + off); off = alup(off + (size_t)N * 64 * 2);

  hipMemsetAsync(deg, 0, (size_t)N * 4, stream);
  hipMemsetAsync(cur, 0, (size_t)N * 4, stream);

  count_deg<<<(E + 255) / 256, 256, 0, stream>>>(ei + E, deg, E);
  dinv_k<<<(N + 255) / 256, 256, 0, stream>>>(deg, dinv, N);
  scan_sum<<<SCAN_B, 256, 0, stream>>>(deg, bsum);
  scan_top<<<1, 256, 0, stream>>>(bsum);
  scan_out<<<SCAN_B, 256, 0, stream>>>(deg, bsum, row_start, E);
  fill_csr<<<(E + 255) / 256, 256, 0, stream>>>(ei, ei + E, row_start, cur, csr, E);

  gemm_scaled<<<(N + 63) / 64, 256, 0, stream>>>(x, W1, dinv, xw, N, 256);
  agg_k<<<(N + 3) / 4, 256, 0, stream>>>(xw, row_start, csr, dinv, b1, z1, N);
  gemm_scaled<<<(N + 63) / 64, 256, 0, stream>>>(z1, W2, dinv, xw, N, 64);
  agg_k<<<(N + 3) / 4, 256, 0, stream>>>(xw, row_start, csr, dinv, b2, z, N);

  cvt_k<<<(N * 64 / 4 + 255) / 256, 256, 0, stream>>>(z, zb, N * 64);

  mlp_kernel<<<1024, 256, 0, stream>>>(ei, zb, Wp1, bp1, Wp2, bp2, Wp3, bp3, pos, E);
  mlp_kernel<<<1024, 256, 0, stream>>>(nei, zb, Wp1, bp1, Wp2, bp2, Wp3, bp3, neg, E);
}

// Round 2
// 737.024 us; speedup vs baseline: 1.1465x; 1.1465x over previous
//
#include <hip/hip_runtime.h>

#define NODES 100000
#define SCAN_B 200
#define CHUNK 500

typedef __attribute__((ext_vector_type(4))) float f4v;
typedef __attribute__((ext_vector_type(8))) short bfx8;
typedef __attribute__((ext_vector_type(4))) float f32x4;
typedef __attribute__((ext_vector_type(4))) unsigned short us4v;
typedef __attribute__((ext_vector_type(2))) unsigned int u2v;
typedef unsigned short ushort_t;
typedef unsigned int uint_t;

__device__ __forceinline__ ushort_t f2b(float f) {
  union { float f; uint_t u; } v; v.f = f;
  return (ushort_t)((v.u + 0x7fffu + ((v.u >> 16) & 1u)) >> 16);
}
__device__ __forceinline__ float b2f(ushort_t h) {
  union { uint_t u; float f; } v; v.u = ((uint_t)h) << 16;
  return v.f;
}

#define MFMA16(A, B, C) __builtin_amdgcn_mfma_f32_16x16x32_bf16((A), (B), (C), 0, 0, 0)

// ---------------- graph prep ----------------

__global__ void count_deg(const int* __restrict__ dst, int* __restrict__ deg, int E) {
  int i = blockIdx.x * 256 + threadIdx.x;
  if (i < E) atomicAdd(&deg[dst[i]], 1);
}

__global__ void dinv_k(const int* __restrict__ deg, float* __restrict__ dinv, int n) {
  int i = blockIdx.x * 256 + threadIdx.x;
  if (i < n) dinv[i] = 1.0f / sqrtf((float)(deg[i] + 1));
}

__global__ void scan_sum(const int* __restrict__ deg, int* __restrict__ bsum) {
  __shared__ int sh[256];
  int b = blockIdx.x, t = threadIdx.x;
  int base = b * CHUNK;
  int v = 0;
  for (int i = t; i < CHUNK; i += 256) v += deg[base + i];
  sh[t] = v;
  __syncthreads();
  for (int s = 128; s > 0; s >>= 1) {
    if (t < s) sh[t] += sh[t + s];
    __syncthreads();
  }
  if (t == 0) bsum[b] = sh[0];
}

__global__ void scan_top(int* __restrict__ bsum) {
  __shared__ int sh[SCAN_B];
  int t = threadIdx.x;
  if (t < SCAN_B) sh[t] = bsum[t];
  __syncthreads();
  if (t == 0) {
    int run = 0;
    for (int i = 0; i < SCAN_B; ++i) { int x = sh[i]; sh[i] = run; run += x; }
  }
  __syncthreads();
  if (t < SCAN_B) bsum[t] = sh[t];
}

__global__ void scan_out(const int* __restrict__ deg, const int* __restrict__ bsum,
                         int* __restrict__ row_start, int E) {
  __shared__ int sh[CHUNK];
  int b = blockIdx.x, t = threadIdx.x;
  int base = b * CHUNK;
  for (int i = t; i < CHUNK; i += 256) sh[i] = deg[base + i];
  __syncthreads();
  if (t == 0) {
    int run = bsum[b];
    for (int i = 0; i < CHUNK; ++i) { int x = sh[i]; sh[i] = run; run += x; }
  }
  __syncthreads();
  for (int i = t; i < CHUNK; i += 256) row_start[base + i] = sh[i];
  if (b == SCAN_B - 1 && t == 0) row_start[NODES] = E;
}

__global__ void fill_csr(const int* __restrict__ src, const int* __restrict__ dst,
                         const int* __restrict__ row_start, int* __restrict__ cursor,
                         int* __restrict__ csr, int E) {
  int i = blockIdx.x * 256 + threadIdx.x;
  if (i < E) {
    int d = dst[i];
    int p = atomicAdd(&cursor[d], 1);
    csr[row_start[d] + p] = src[i];
  }
}

// ---------------- conv path: split-bf16 MFMA GEMM ----------------
// out[r][c] = dinv[r] * sum_k A[r][k]*W[k][c]   (A: [n x K] row-major, W: [K x 64])
// block = 4 waves; 32 rows x 64 cols per block; wave w owns cols [16w,16w+16).
// x tile staged in LDS pre-split to hi/lo bf16, XOR-swizzled for b128 reads.
template <int K>
__global__ __launch_bounds__(256) void conv_gemm(
    const float* __restrict__ A, const float* __restrict__ W,
    const float* __restrict__ dinv, float* __restrict__ out, int n) {
  constexpr int KT = K / 32;       // k-tiles of 32
  constexpr int SEGS = K / 8;      // 8-elem segments per row
  __shared__ __align__(16) ushort_t lhi[32 * K];
  __shared__ __align__(16) ushort_t llo[32 * K];

  int tid = threadIdx.x;
  int lane = tid & 63, wave = tid >> 6;
  int q = lane & 15, g = lane >> 4;
  int c0 = wave * 16;
  int r0 = blockIdx.x * 32;

  // B-frags (W hi/lo) in registers, loaded once. B[k][c]: col=q, k=g*8+j.
  bfx8 bhi[KT], blo[KT];
#pragma unroll
  for (int kt = 0; kt < KT; ++kt) {
    bfx8 h, l;
#pragma unroll
    for (int j = 0; j < 8; ++j) {
      float w = W[(size_t)(kt * 32 + g * 8 + j) * 64 + c0 + q];
      ushort_t hb = f2b(w);
      float lo = w - b2f(hb);
      h[j] = (short)hb;
      l[j] = (short)f2b(lo);
    }
    bhi[kt] = h;
    blo[kt] = l;
  }

  // stage x tile -> LDS (hi/lo bf16), swizzle byte ^= (row&7)<<4
  for (int idx = tid; idx < 32 * SEGS; idx += 256) {
    int row = idx / SEGS, s = idx % SEGS;
    const float* p = A + (size_t)(r0 + row) * K + s * 8;
    f4v v0 = *(const f4v*)p;
    f4v v1 = *(const f4v*)(p + 4);
    bfx8 h8, l8;
#pragma unroll
    for (int j = 0; j < 4; ++j) {
      ushort_t hb = f2b(v0[j]);
      h8[j] = (short)hb;
      l8[j] = (short)f2b(v0[j] - b2f(hb));
      ushort_t hb1 = f2b(v1[j]);
      h8[4 + j] = (short)hb1;
      l8[4 + j] = (short)f2b(v1[j] - b2f(hb1));
    }
    int boff = row * (K * 2) + ((s * 16) ^ ((row & 7) << 4));
    *(bfx8*)((char*)lhi + boff) = h8;
    *(bfx8*)((char*)llo + boff) = l8;
  }
  __syncthreads();

  f32x4 hh[2], hl[2], lh[2];
#pragma unroll
  for (int rt = 0; rt < 2; ++rt) {
    hh[rt] = (f32x4){0.f, 0.f, 0.f, 0.f};
    hl[rt] = (f32x4){0.f, 0.f, 0.f, 0.f};
    lh[rt] = (f32x4){0.f, 0.f, 0.f, 0.f};
  }
#pragma unroll
  for (int kt = 0; kt < KT; ++kt) {
#pragma unroll
    for (int rt = 0; rt < 2; ++rt) {
      int row = rt * 16 + q;
      int boff = row * (K * 2) + (((kt * 64 + g * 16)) ^ ((row & 7) << 4));
      bfx8 ah = *(const bfx8*)((const char*)lhi + boff);
      bfx8 al = *(const bfx8*)((const char*)llo + boff);
      hh[rt] = MFMA16(ah, bhi[kt], hh[rt]);
      hl[rt] = MFMA16(ah, blo[kt], hl[rt]);
      lh[rt] = MFMA16(al, bhi[kt], lh[rt]);
    }
  }

#pragma unroll
  for (int rt = 0; rt < 2; ++rt) {
    f32x4 s = hh[rt] + hl[rt] + lh[rt];
#pragma unroll
    for (int j = 0; j < 4; ++j) {
      int row = r0 + rt * 16 + g * 4 + j;
      if (row < n) out[(size_t)row * 64 + c0 + q] = s[j] * dinv[row];
    }
  }
}

// out[i][c] = relu( dinv[i] * (P[i][c] + sum_{s in nbr(i)} P[s][c]) + bias[c] )
// optionally also emit bf16 copy (zb != nullptr)
__global__ void agg_k(const float* __restrict__ P, const int* __restrict__ row_start,
                      const int* __restrict__ csr, const float* __restrict__ dinv,
                      const float* __restrict__ bias, float* __restrict__ out,
                      ushort_t* __restrict__ zb, int n) {
  int wave = threadIdx.x >> 6, lane = threadIdx.x & 63;
  int i = blockIdx.x * 4 + wave;
  if (i >= n) return;
  float acc = P[(size_t)i * 64 + lane];
  int beg = row_start[i], end = row_start[i + 1];
  float di = dinv[i];
  for (int j = beg; j < end; ++j) {
    int s = csr[j];
    acc += P[(size_t)s * 64 + lane];
  }
  float v = fmaxf(acc * di + bias[lane], 0.0f);
  out[(size_t)i * 64 + lane] = v;
  if (zb) zb[(size_t)i * 64 + lane] = f2b(v);
}

// ---------------- edge MLP (bf16 MFMA) ----------------
__global__ __launch_bounds__(256, 2) void mlp_kernel(
    const int* __restrict__ ei, const ushort_t* __restrict__ zb,
    const float* __restrict__ Wp1, const float* __restrict__ bp1,
    const float* __restrict__ Wp2, const float* __restrict__ bp2,
    const float* __restrict__ Wp3, const float* __restrict__ bp3,
    float* __restrict__ out, int E) {
  __shared__ __align__(16) char WT1[32768];      // Wp1^T, [n=128][k=128] bf16, XOR-swizzled rows
  __shared__ __align__(16) char H1[4][8192];     // per-wave h1, [edge=32][n=128] bf16, swizzled

  int tid = threadIdx.x;
  for (int idx = tid; idx < 128 * 128; idx += 256) {
    int k = idx >> 7, n = idx & 127;
    int boff = n * 256 + (((k * 2) ^ ((n & 7) << 4)));
    *(ushort_t*)(WT1 + boff) = f2b(Wp1[idx]);
  }
  __syncthreads();

  int lane = tid & 63, wave = tid >> 6;
  int q = lane & 15, g = lane >> 4;
  char* H1w = &H1[wave][0];

  bfx8 wf2r[16];
#pragma unroll
  for (int t2 = 0; t2 < 4; ++t2)
#pragma unroll
    for (int kk = 0; kk < 4; ++kk) {
      bfx8 v;
#pragma unroll
      for (int j = 0; j < 8; ++j) {
        int k = kk * 32 + g * 8 + j;
        int n = t2 * 16 + q;
        v[j] = (short)f2b(Wp2[k * 64 + n]);
      }
      wf2r[t2 * 4 + kk] = v;
    }
  float b1r[32], b2r[16], w3r[16];
#pragma unroll
  for (int t = 0; t < 8; ++t)
#pragma unroll
    for (int j = 0; j < 4; ++j) b1r[t * 4 + j] = bp1[t * 16 + g * 4 + j];
#pragma unroll
  for (int t = 0; t < 4; ++t)
#pragma unroll
    for (int j = 0; j < 4; ++j) {
      b2r[t * 4 + j] = bp2[t * 16 + g * 4 + j];
      w3r[t * 4 + j] = Wp3[t * 16 + g * 4 + j];
    }
  float bp3v = bp3[0];

  int ntile = E >> 7;
  for (int tile = blockIdx.x; tile < ntile; tile += gridDim.x) {
    int ebase = (tile << 7) + (wave << 5);

    bfx8 af[2][4];
#pragma unroll
    for (int eb = 0; eb < 2; ++eb) {
      int e = ebase + eb * 16 + q;
      int s = ei[e], d = ei[E + e];
#pragma unroll
      for (int kk = 0; kk < 4; ++kk) {
        int node = (kk < 2) ? s : d;
        int off = ((kk & 1) << 5) + (g << 3);
        af[eb][kk] = *(const bfx8*)(zb + (size_t)node * 64 + off);
      }
    }

#pragma unroll
    for (int t = 0; t < 8; ++t) {
      f32x4 acc1[2];
      acc1[0] = (f32x4){0.f, 0.f, 0.f, 0.f};
      acc1[1] = (f32x4){0.f, 0.f, 0.f, 0.f};
#pragma unroll
      for (int kk = 0; kk < 4; ++kk) {
        int n = t * 16 + q;
        bfx8 wf = *(const bfx8*)(WT1 + n * 256 + (((kk * 64 + g * 16)) ^ ((n & 7) << 4)));
        acc1[0] = MFMA16(wf, af[0][kk], acc1[0]);
        acc1[1] = MFMA16(wf, af[1][kk], acc1[1]);
      }
#pragma unroll
      for (int eb = 0; eb < 2; ++eb) {
        float v0 = fmaxf(acc1[eb][0] + b1r[t * 4 + 0], 0.f);
        float v1 = fmaxf(acc1[eb][1] + b1r[t * 4 + 1], 0.f);
        float v2 = fmaxf(acc1[eb][2] + b1r[t * 4 + 2], 0.f);
        float v3 = fmaxf(acc1[eb][3] + b1r[t * 4 + 3], 0.f);
        u2v pk;
        pk[0] = (uint_t)f2b(v0) | ((uint_t)f2b(v1) << 16);
        pk[1] = (uint_t)f2b(v2) | ((uint_t)f2b(v3) << 16);
        int row = eb * 16 + q;
        int bcol = ((t * 32 + g * 8)) ^ ((row & 7) << 4);
        *(u2v*)(H1w + row * 256 + bcol) = pk;
      }
    }
    asm volatile("s_waitcnt lgkmcnt(0)" ::: "memory");

#pragma unroll
    for (int eb = 0; eb < 2; ++eb) {
      f32x4 acc2[4];
#pragma unroll
      for (int t2 = 0; t2 < 4; ++t2) acc2[t2] = (f32x4){0.f, 0.f, 0.f, 0.f};
#pragma unroll
      for (int kk = 0; kk < 4; ++kk) {
        int row = eb * 16 + q;
        bfx8 hf = *(const bfx8*)(H1w + row * 256 + (((kk * 64 + g * 16)) ^ ((row & 7) << 4)));
#pragma unroll
        for (int t2 = 0; t2 < 4; ++t2) acc2[t2] = MFMA16(wf2r[t2 * 4 + kk], hf, acc2[t2]);
      }
      float sacc = 0.f;
#pragma unroll
      for (int t2 = 0; t2 < 4; ++t2)
#pragma unroll
        for (int j = 0; j < 4; ++j) {
          float h = fmaxf(acc2[t2][j] + b2r[t2 * 4 + j], 0.f);
          sacc += h * w3r[t2 * 4 + j];
        }
      sacc += __shfl_xor(sacc, 16);
      sacc += __shfl_xor(sacc, 32);
      if (g == 0) out[ebase + eb * 16 + q] = sacc + bp3v;
    }
  }
}

// ---------------- launch ----------------

static inline size_t alup(size_t x) { return (x + 511) & ~(size_t)511; }

extern "C" void kernel_launch(void* const* d_in, const int* in_sizes, int n_in,
                              void* d_out, int out_size, void* d_ws, size_t ws_size,
                              hipStream_t stream) {
  const float* x = (const float*)d_in[0];
  const int* ei = (const int*)d_in[1];
  const int* nei = (const int*)d_in[2];
  const float* W1 = (const float*)d_in[3];
  const float* b1 = (const float*)d_in[4];
  const float* W2 = (const float*)d_in[5];
  const float* b2 = (const float*)d_in[6];
  const float* Wp1 = (const float*)d_in[7];
  const float* bp1 = (const float*)d_in[8];
  const float* Wp2 = (const float*)d_in[9];
  const float* bp2 = (const float*)d_in[10];
  const float* Wp3 = (const float*)d_in[11];
  const float* bp3 = (const float*)d_in[12];

  const int N = NODES;
  const int E = in_sizes[1] / 2;

  float* pos = (float*)d_out;
  float* neg = pos + E;
  float* z = pos + (size_t)2 * E;

  char* w = (char*)d_ws;
  size_t off = 0;
  int* deg = (int*)(w + off); off = alup(off + (size_t)N * 4);
  int* cur = (int*)(w + off); off = alup(off + (size_t)N * 4);
  float* dinv = (float*)(w + off); off = alup(off + (size_t)N * 4);
  int* bsum = (int*)(w + off); off = alup(off + 256 * 4);
  int* row_start = (int*)(w + off); off = alup(off + (size_t)(N + 1) * 4);
  int* csr = (int*)(w + off); off = alup(off + (size_t)E * 4);
  float* xw = (float*)(w + off); off = alup(off + (size_t)N * 64 * 4);
  float* z1 = (float*)(w + off); off = alup(off + (size_t)N * 64 * 4);
  ushort_t* zb = (ushort_t*)(w + off); off = alup(off + (size_t)N * 64 * 2);

  hipMemsetAsync(deg, 0, (size_t)N * 4, stream);
  hipMemsetAsync(cur, 0, (size_t)N * 4, stream);

  count_deg<<<(E + 255) / 256, 256, 0, stream>>>(ei + E, deg, E);
  dinv_k<<<(N + 255) / 256, 256, 0, stream>>>(deg, dinv, N);
  scan_sum<<<SCAN_B, 256, 0, stream>>>(deg, bsum);
  scan_top<<<1, 256, 0, stream>>>(bsum);
  scan_out<<<SCAN_B, 256, 0, stream>>>(deg, bsum, row_start, E);
  fill_csr<<<(E + 255) / 256, 256, 0, stream>>>(ei, ei + E, row_start, cur, csr, E);

  conv_gemm<256><<<(N + 31) / 32, 256, 0, stream>>>(x, W1, dinv, xw, N);
  agg_k<<<(N + 3) / 4, 256, 0, stream>>>(xw, row_start, csr, dinv, b1, z1, nullptr, N);
  conv_gemm<64><<<(N + 31) / 32, 256, 0, stream>>>(z1, W2, dinv, xw, N);
  agg_k<<<(N + 3) / 4, 256, 0, stream>>>(xw, row_start, csr, dinv, b2, z, zb, N);

  mlp_kernel<<<1024, 256, 0, stream>>>(ei, zb, Wp1, bp1, Wp2, bp2, Wp3, bp3, pos, E);
  mlp_kernel<<<1024, 256, 0, stream>>>(nei, zb, Wp1, bp1, Wp2, bp2, Wp3, bp3, neg, E);
}

// Round 3
// 566.622 us; speedup vs baseline: 1.4913x; 1.3007x over previous
//
#include <hip/hip_runtime.h>

#define NODES 100000
#define SCAN_B 200
#define CHUNK 500

typedef __attribute__((ext_vector_type(4))) float f4v;
typedef __attribute__((ext_vector_type(8))) short bfx8;
typedef __attribute__((ext_vector_type(4))) float f32x4;
typedef __attribute__((ext_vector_type(4))) unsigned short us4v;
typedef __attribute__((ext_vector_type(2))) unsigned int u2v;
typedef unsigned short ushort_t;
typedef unsigned int uint_t;

__device__ __forceinline__ ushort_t f2b(float f) {
  union { float f; uint_t u; } v; v.f = f;
  return (ushort_t)((v.u + 0x7fffu + ((v.u >> 16) & 1u)) >> 16);
}
__device__ __forceinline__ float b2f(ushort_t h) {
  union { uint_t u; float f; } v; v.u = ((uint_t)h) << 16;
  return v.f;
}

#define MFMA16(A, B, C) __builtin_amdgcn_mfma_f32_16x16x32_bf16((A), (B), (C), 0, 0, 0)

// ---------------- graph prep ----------------

__global__ void count_deg(const int* __restrict__ dst, int* __restrict__ deg, int E) {
  int i = blockIdx.x * 256 + threadIdx.x;
  if (i < E) atomicAdd(&deg[dst[i]], 1);
}

__global__ void dinv_k(const int* __restrict__ deg, float* __restrict__ dinv, int n) {
  int i = blockIdx.x * 256 + threadIdx.x;
  if (i < n) dinv[i] = 1.0f / sqrtf((float)(deg[i] + 1));
}

__global__ void scan_sum(const int* __restrict__ deg, int* __restrict__ bsum) {
  __shared__ int sh[256];
  int b = blockIdx.x, t = threadIdx.x;
  int base = b * CHUNK;
  int v = 0;
  for (int i = t; i < CHUNK; i += 256) v += deg[base + i];
  sh[t] = v;
  __syncthreads();
  for (int s = 128; s > 0; s >>= 1) {
    if (t < s) sh[t] += sh[t + s];
    __syncthreads();
  }
  if (t == 0) bsum[b] = sh[0];
}

__global__ void scan_top(int* __restrict__ bsum) {
  __shared__ int sh[SCAN_B];
  int t = threadIdx.x;
  if (t < SCAN_B) sh[t] = bsum[t];
  __syncthreads();
  if (t == 0) {
    int run = 0;
    for (int i = 0; i < SCAN_B; ++i) { int x = sh[i]; sh[i] = run; run += x; }
  }
  __syncthreads();
  if (t < SCAN_B) bsum[t] = sh[t];
}

__global__ void scan_out(const int* __restrict__ deg, const int* __restrict__ bsum,
                         int* __restrict__ row_start, int E) {
  __shared__ int sh[CHUNK];
  int b = blockIdx.x, t = threadIdx.x;
  int base = b * CHUNK;
  for (int i = t; i < CHUNK; i += 256) sh[i] = deg[base + i];
  __syncthreads();
  if (t == 0) {
    int run = bsum[b];
    for (int i = 0; i < CHUNK; ++i) { int x = sh[i]; sh[i] = run; run += x; }
  }
  __syncthreads();
  for (int i = t; i < CHUNK; i += 256) row_start[base + i] = sh[i];
  if (b == SCAN_B - 1 && t == 0) row_start[NODES] = E;
}

__global__ void fill_csr(const int* __restrict__ src, const int* __restrict__ dst,
                         const int* __restrict__ row_start, int* __restrict__ cursor,
                         int* __restrict__ csr, int E) {
  int i = blockIdx.x * 256 + threadIdx.x;
  if (i < E) {
    int d = dst[i];
    int p = atomicAdd(&cursor[d], 1);
    csr[row_start[d] + p] = src[i];
  }
}

// ---------------- conv path: split-bf16 MFMA GEMM ----------------
template <int K>
__global__ __launch_bounds__(256) void conv_gemm(
    const float* __restrict__ A, const float* __restrict__ W,
    const float* __restrict__ dinv, float* __restrict__ out, int n) {
  constexpr int KT = K / 32;
  constexpr int SEGS = K / 8;
  __shared__ __align__(16) ushort_t lhi[32 * K];
  __shared__ __align__(16) ushort_t llo[32 * K];

  int tid = threadIdx.x;
  int lane = tid & 63, wave = tid >> 6;
  int q = lane & 15, g = lane >> 4;
  int c0 = wave * 16;
  int r0 = blockIdx.x * 32;

  bfx8 bhi[KT], blo[KT];
#pragma unroll
  for (int kt = 0; kt < KT; ++kt) {
    bfx8 h, l;
#pragma unroll
    for (int j = 0; j < 8; ++j) {
      float w = W[(size_t)(kt * 32 + g * 8 + j) * 64 + c0 + q];
      ushort_t hb = f2b(w);
      float lo = w - b2f(hb);
      h[j] = (short)hb;
      l[j] = (short)f2b(lo);
    }
    bhi[kt] = h;
    blo[kt] = l;
  }

  for (int idx = tid; idx < 32 * SEGS; idx += 256) {
    int row = idx / SEGS, s = idx % SEGS;
    const float* p = A + (size_t)(r0 + row) * K + s * 8;
    f4v v0 = *(const f4v*)p;
    f4v v1 = *(const f4v*)(p + 4);
    bfx8 h8, l8;
#pragma unroll
    for (int j = 0; j < 4; ++j) {
      ushort_t hb = f2b(v0[j]);
      h8[j] = (short)hb;
      l8[j] = (short)f2b(v0[j] - b2f(hb));
      ushort_t hb1 = f2b(v1[j]);
      h8[4 + j] = (short)hb1;
      l8[4 + j] = (short)f2b(v1[j] - b2f(hb1));
    }
    int boff = row * (K * 2) + ((s * 16) ^ ((row & 7) << 4));
    *(bfx8*)((char*)lhi + boff) = h8;
    *(bfx8*)((char*)llo + boff) = l8;
  }
  __syncthreads();

  f32x4 hh[2], hl[2], lh[2];
#pragma unroll
  for (int rt = 0; rt < 2; ++rt) {
    hh[rt] = (f32x4){0.f, 0.f, 0.f, 0.f};
    hl[rt] = (f32x4){0.f, 0.f, 0.f, 0.f};
    lh[rt] = (f32x4){0.f, 0.f, 0.f, 0.f};
  }
#pragma unroll
  for (int kt = 0; kt < KT; ++kt) {
#pragma unroll
    for (int rt = 0; rt < 2; ++rt) {
      int row = rt * 16 + q;
      int boff = row * (K * 2) + (((kt * 64 + g * 16)) ^ ((row & 7) << 4));
      bfx8 ah = *(const bfx8*)((const char*)lhi + boff);
      bfx8 al = *(const bfx8*)((const char*)llo + boff);
      hh[rt] = MFMA16(ah, bhi[kt], hh[rt]);
      hl[rt] = MFMA16(ah, blo[kt], hl[rt]);
      lh[rt] = MFMA16(al, bhi[kt], lh[rt]);
    }
  }

#pragma unroll
  for (int rt = 0; rt < 2; ++rt) {
    f32x4 s = hh[rt] + hl[rt] + lh[rt];
#pragma unroll
    for (int j = 0; j < 4; ++j) {
      int row = r0 + rt * 16 + g * 4 + j;
      if (row < n) out[(size_t)row * 64 + c0 + q] = s[j] * dinv[row];
    }
  }
}

// out[i][c] = relu( dinv[i] * (P[i][c] + sum_{s in nbr(i)} P[s][c]) + bias[c] )
// 8-wide unrolled neighbor gather for memory-level parallelism.
__global__ void agg_k(const float* __restrict__ P, const int* __restrict__ row_start,
                      const int* __restrict__ csr, const float* __restrict__ dinv,
                      const float* __restrict__ bias, float* __restrict__ out,
                      ushort_t* __restrict__ zb, int n) {
  int wave = threadIdx.x >> 6, lane = threadIdx.x & 63;
  int i = blockIdx.x * 4 + wave;
  if (i >= n) return;
  const float* Pl = P + lane;
  float a0 = Pl[(size_t)i * 64];
  float a1 = 0.f, a2 = 0.f, a3 = 0.f;
  int beg = row_start[i], end = row_start[i + 1];
  int j = beg;
  for (; j + 8 <= end; j += 8) {
    int s0 = csr[j + 0], s1 = csr[j + 1], s2 = csr[j + 2], s3 = csr[j + 3];
    int s4 = csr[j + 4], s5 = csr[j + 5], s6 = csr[j + 6], s7 = csr[j + 7];
    float v0 = Pl[(size_t)s0 * 64];
    float v1 = Pl[(size_t)s1 * 64];
    float v2 = Pl[(size_t)s2 * 64];
    float v3 = Pl[(size_t)s3 * 64];
    float v4 = Pl[(size_t)s4 * 64];
    float v5 = Pl[(size_t)s5 * 64];
    float v6 = Pl[(size_t)s6 * 64];
    float v7 = Pl[(size_t)s7 * 64];
    a0 += v0; a1 += v1; a2 += v2; a3 += v3;
    a0 += v4; a1 += v5; a2 += v6; a3 += v7;
  }
  if (j + 4 <= end) {
    int s0 = csr[j + 0], s1 = csr[j + 1], s2 = csr[j + 2], s3 = csr[j + 3];
    float v0 = Pl[(size_t)s0 * 64];
    float v1 = Pl[(size_t)s1 * 64];
    float v2 = Pl[(size_t)s2 * 64];
    float v3 = Pl[(size_t)s3 * 64];
    a0 += v0; a1 += v1; a2 += v2; a3 += v3;
    j += 4;
  }
  for (; j < end; ++j) a1 += Pl[(size_t)csr[j] * 64];
  float acc = (a0 + a1) + (a2 + a3);
  float v = fmaxf(acc * dinv[i] + bias[lane], 0.0f);
  out[(size_t)i * 64 + lane] = v;
  if (zb) zb[(size_t)i * 64 + lane] = f2b(v);
}

// ---------------- edge MLP (bf16 MFMA) ----------------
__global__ __launch_bounds__(256, 2) void mlp_kernel(
    const int* __restrict__ ei, const ushort_t* __restrict__ zb,
    const float* __restrict__ Wp1, const float* __restrict__ bp1,
    const float* __restrict__ Wp2, const float* __restrict__ bp2,
    const float* __restrict__ Wp3, const float* __restrict__ bp3,
    float* __restrict__ out, int E) {
  __shared__ __align__(16) char WT1[32768];
  __shared__ __align__(16) char H1[4][8192];

  int tid = threadIdx.x;
  for (int idx = tid; idx < 128 * 128; idx += 256) {
    int k = idx >> 7, n = idx & 127;
    int boff = n * 256 + (((k * 2) ^ ((n & 7) << 4)));
    *(ushort_t*)(WT1 + boff) = f2b(Wp1[idx]);
  }
  __syncthreads();

  int lane = tid & 63, wave = tid >> 6;
  int q = lane & 15, g = lane >> 4;
  char* H1w = &H1[wave][0];

  bfx8 wf2r[16];
#pragma unroll
  for (int t2 = 0; t2 < 4; ++t2)
#pragma unroll
    for (int kk = 0; kk < 4; ++kk) {
      bfx8 v;
#pragma unroll
      for (int j = 0; j < 8; ++j) {
        int k = kk * 32 + g * 8 + j;
        int n = t2 * 16 + q;
        v[j] = (short)f2b(Wp2[k * 64 + n]);
      }
      wf2r[t2 * 4 + kk] = v;
    }
  float b1r[32], b2r[16], w3r[16];
#pragma unroll
  for (int t = 0; t < 8; ++t)
#pragma unroll
    for (int j = 0; j < 4; ++j) b1r[t * 4 + j] = bp1[t * 16 + g * 4 + j];
#pragma unroll
  for (int t = 0; t < 4; ++t)
#pragma unroll
    for (int j = 0; j < 4; ++j) {
      b2r[t * 4 + j] = bp2[t * 16 + g * 4 + j];
      w3r[t * 4 + j] = Wp3[t * 16 + g * 4 + j];
    }
  float bp3v = bp3[0];

  int ntile = E >> 7;
  for (int tile = blockIdx.x; tile < ntile; tile += gridDim.x) {
    int ebase = (tile << 7) + (wave << 5);

    bfx8 af[2][4];
#pragma unroll
    for (int eb = 0; eb < 2; ++eb) {
      int e = ebase + eb * 16 + q;
      int s = ei[e], d = ei[E + e];
#pragma unroll
      for (int kk = 0; kk < 4; ++kk) {
        int node = (kk < 2) ? s : d;
        int off = ((kk & 1) << 5) + (g << 3);
        af[eb][kk] = *(const bfx8*)(zb + (size_t)node * 64 + off);
      }
    }

#pragma unroll
    for (int t = 0; t < 8; ++t) {
      f32x4 acc1[2];
      acc1[0] = (f32x4){0.f, 0.f, 0.f, 0.f};
      acc1[1] = (f32x4){0.f, 0.f, 0.f, 0.f};
#pragma unroll
      for (int kk = 0; kk < 4; ++kk) {
        int n = t * 16 + q;
        bfx8 wf = *(const bfx8*)(WT1 + n * 256 + (((kk * 64 + g * 16)) ^ ((n & 7) << 4)));
        acc1[0] = MFMA16(wf, af[0][kk], acc1[0]);
        acc1[1] = MFMA16(wf, af[1][kk], acc1[1]);
      }
#pragma unroll
      for (int eb = 0; eb < 2; ++eb) {
        float v0 = fmaxf(acc1[eb][0] + b1r[t * 4 + 0], 0.f);
        float v1 = fmaxf(acc1[eb][1] + b1r[t * 4 + 1], 0.f);
        float v2 = fmaxf(acc1[eb][2] + b1r[t * 4 + 2], 0.f);
        float v3 = fmaxf(acc1[eb][3] + b1r[t * 4 + 3], 0.f);
        u2v pk;
        pk[0] = (uint_t)f2b(v0) | ((uint_t)f2b(v1) << 16);
        pk[1] = (uint_t)f2b(v2) | ((uint_t)f2b(v3) << 16);
        int row = eb * 16 + q;
        int bcol = ((t * 32 + g * 8)) ^ ((row & 7) << 4);
        *(u2v*)(H1w + row * 256 + bcol) = pk;
      }
    }
    asm volatile("s_waitcnt lgkmcnt(0)" ::: "memory");

#pragma unroll
    for (int eb = 0; eb < 2; ++eb) {
      f32x4 acc2[4];
#pragma unroll
      for (int t2 = 0; t2 < 4; ++t2) acc2[t2] = (f32x4){0.f, 0.f, 0.f, 0.f};
#pragma unroll
      for (int kk = 0; kk < 4; ++kk) {
        int row = eb * 16 + q;
        bfx8 hf = *(const bfx8*)(H1w + row * 256 + (((kk * 64 + g * 16)) ^ ((row & 7) << 4)));
#pragma unroll
        for (int t2 = 0; t2 < 4; ++t2) acc2[t2] = MFMA16(wf2r[t2 * 4 + kk], hf, acc2[t2]);
      }
      float sacc = 0.f;
#pragma unroll
      for (int t2 = 0; t2 < 4; ++t2)
#pragma unroll
        for (int j = 0; j < 4; ++j) {
          float h = fmaxf(acc2[t2][j] + b2r[t2 * 4 + j], 0.f);
          sacc += h * w3r[t2 * 4 + j];
        }
      sacc += __shfl_xor(sacc, 16);
      sacc += __shfl_xor(sacc, 32);
      if (g == 0) out[ebase + eb * 16 + q] = sacc + bp3v;
    }
  }
}

// ---------------- launch ----------------

static inline size_t alup(size_t x) { return (x + 511) & ~(size_t)511; }

extern "C" void kernel_launch(void* const* d_in, const int* in_sizes, int n_in,
                              void* d_out, int out_size, void* d_ws, size_t ws_size,
                              hipStream_t stream) {
  const float* x = (const float*)d_in[0];
  const int* ei = (const int*)d_in[1];
  const int* nei = (const int*)d_in[2];
  const float* W1 = (const float*)d_in[3];
  const float* b1 = (const float*)d_in[4];
  const float* W2 = (const float*)d_in[5];
  const float* b2 = (const float*)d_in[6];
  const float* Wp1 = (const float*)d_in[7];
  const float* bp1 = (const float*)d_in[8];
  const float* Wp2 = (const float*)d_in[9];
  const float* bp2 = (const float*)d_in[10];
  const float* Wp3 = (const float*)d_in[11];
  const float* bp3 = (const float*)d_in[12];

  const int N = NODES;
  const int E = in_sizes[1] / 2;

  float* pos = (float*)d_out;
  float* neg = pos + E;
  float* z = pos + (size_t)2 * E;

  char* w = (char*)d_ws;
  size_t off = 0;
  int* deg = (int*)(w + off); off = alup(off + (size_t)N * 4);
  int* cur = (int*)(w + off); off = alup(off + (size_t)N * 4);
  float* dinv = (float*)(w + off); off = alup(off + (size_t)N * 4);
  int* bsum = (int*)(w + off); off = alup(off + 256 * 4);
  int* row_start = (int*)(w + off); off = alup(off + (size_t)(N + 1) * 4);
  int* csr = (int*)(w + off); off = alup(off + (size_t)E * 4);
  float* xw = (float*)(w + off); off = alup(off + (size_t)N * 64 * 4);
  float* z1 = (float*)(w + off); off = alup(off + (size_t)N * 64 * 4);
  ushort_t* zb = (ushort_t*)(w + off); off = alup(off + (size_t)N * 64 * 2);

  hipMemsetAsync(deg, 0, (size_t)N * 4, stream);
  hipMemsetAsync(cur, 0, (size_t)N * 4, stream);

  count_deg<<<(E + 255) / 256, 256, 0, stream>>>(ei + E, deg, E);
  dinv_k<<<(N + 255) / 256, 256, 0, stream>>>(deg, dinv, N);
  scan_sum<<<SCAN_B, 256, 0, stream>>>(deg, bsum);
  scan_top<<<1, 256, 0, stream>>>(bsum);
  scan_out<<<SCAN_B, 256, 0, stream>>>(deg, bsum, row_start, E);
  fill_csr<<<(E + 255) / 256, 256, 0, stream>>>(ei, ei + E, row_start, cur, csr, E);

  conv_gemm<256><<<(N + 31) / 32, 256, 0, stream>>>(x, W1, dinv, xw, N);
  agg_k<<<(N + 3) / 4, 256, 0, stream>>>(xw, row_start, csr, dinv, b1, z1, nullptr, N);
  conv_gemm<64><<<(N + 31) / 32, 256, 0, stream>>>(z1, W2, dinv, xw, N);
  agg_k<<<(N + 3) / 4, 256, 0, stream>>>(xw, row_start, csr, dinv, b2, z, zb, N);

  mlp_kernel<<<1024, 256, 0, stream>>>(ei, zb, Wp1, bp1, Wp2, bp2, Wp3, bp3, pos, E);
  mlp_kernel<<<1024, 256, 0, stream>>>(nei, zb, Wp1, bp1, Wp2, bp2, Wp3, bp3, neg, E);
}